// Round 7
// baseline (184.644 us; speedup 1.0000x reference)
//
#include <hip/hip_runtime.h>
#include <math.h>

#define V 16384
#define D 256
#define NH 256
#define THREE_NH 768
#define IDIM 1024
#define LN_EPS 1e-12f

typedef short s16x8 __attribute__((ext_vector_type(8)));
typedef float f32x4 __attribute__((ext_vector_type(4)));

__device__ inline unsigned short f2bf(float f) {
    unsigned u = __float_as_uint(f);
    u += 0x7fffu + ((u >> 16) & 1u);          // RNE
    return (unsigned short)(u >> 16);
}
__device__ inline float bf2f(unsigned short s) {
    return __uint_as_float(((unsigned)s) << 16);
}
__device__ inline float bflo(unsigned v) { return __uint_as_float(v << 16); }
__device__ inline float bfhi(unsigned v) { return __uint_as_float(v & 0xffff0000u); }

// async global->LDS, 16B per lane. LDS dest = wave-uniform base + lane*16.
__device__ inline void gl2lds16(const unsigned short* g, unsigned short* l) {
    __builtin_amdgcn_global_load_lds(
        (__attribute__((address_space(1))) void*)(g),
        (__attribute__((address_space(3))) void*)(l), 16, 0, 0);
}

// Stage ROWS_T x 64 bf16 tile (row-major, leading dim ldk) into LDS.
// 16B chunk c of row r stored at chunk slot c ^ (r&7) (XOR swizzle on the
// global side; LDS write order stays lane-contiguous for global_load_lds).
template <int ROWS_T>
__device__ inline void stage(const unsigned short* __restrict__ src, size_t row0,
                             int ldk, int k0, unsigned short* lds, int wv, int lane) {
    constexpr int PER_WAVE = ROWS_T / 32;     // 1KB segments per wave
    #pragma unroll
    for (int i = 0; i < PER_WAVE; ++i) {
        const int seg = wv * PER_WAVE + i;
        const int r = seg * 8 + (lane >> 3);
        const int c = (lane & 7) ^ (r & 7);
        gl2lds16(src + (row0 + (size_t)r) * ldk + k0 + c * 8, lds + seg * 512);
    }
}

// read one 8-elem bf16 fragment (16B) for (row, chunk) from swizzled tile
__device__ inline s16x8 fragld(const unsigned short* lds, int row, int chunk) {
    return *(const s16x8*)&lds[row * 64 + ((chunk ^ (row & 7)) << 3)];
}

// ---------------------------------------------------------------------------
// prep: one launch for all conversions.
// blocks [0,768): W transposes (fp32 KxN -> bf16 NxK); [768,4864): X -> bf16.
// ---------------------------------------------------------------------------
__global__ __launch_bounds__(256) void prep(const float* __restrict__ X,
                                            unsigned short* __restrict__ Xb,
                                            const float* __restrict__ Wqkv,
                                            const float* __restrict__ Wo,
                                            const float* __restrict__ Wi,
                                            const float* __restrict__ Wo2,
                                            unsigned short* __restrict__ WqkvT,
                                            unsigned short* __restrict__ WoT,
                                            unsigned short* __restrict__ WiT,
                                            unsigned short* __restrict__ Wo2T) {
    const int b = blockIdx.x, t = threadIdx.x;
    if (b >= 768) {
        int i = (b - 768) * 256 + t;
        float4 v = ((const float4*)X)[i];
        ushort4 o;
        o.x = f2bf(v.x); o.y = f2bf(v.y); o.z = f2bf(v.z); o.w = f2bf(v.w);
        ((ushort4*)Xb)[i] = o;
        return;
    }
    __shared__ float tile[32][33];
    const float* W; unsigned short* Wt; int K, N, bx, by;
    if (b < 192)      { W = Wqkv; Wt = WqkvT; K = 256;  N = 768;  bx = b & 7;          by = b >> 3; }
    else if (b < 256) { W = Wo;   Wt = WoT;   K = 256;  N = 256;  bx = (b - 192) & 7;  by = (b - 192) >> 3; }
    else if (b < 512) { W = Wi;   Wt = WiT;   K = 256;  N = 1024; bx = (b - 256) & 7;  by = (b - 256) >> 3; }
    else              { W = Wo2;  Wt = Wo2T;  K = 1024; N = 256;  bx = (b - 512) & 31; by = (b - 512) >> 5; }
    const int k0 = bx * 32, n0 = by * 32;
    #pragma unroll
    for (int p = 0; p < 4; ++p) {
        int idx = t + p * 256, r = idx >> 5, c = idx & 31;
        tile[r][c] = W[(size_t)(k0 + r) * N + n0 + c];
    }
    __syncthreads();
    #pragma unroll
    for (int p = 0; p < 4; ++p) {
        int idx = t + p * 256, r = idx >> 5, c = idx & 31;
        Wt[(size_t)(n0 + r) * K + k0 + c] = f2bf(tile[c][r]);
    }
}

// ---------------------------------------------------------------------------
// gemm128<K,N,EPI>: C(bf16, MxN) = A(bf16, MxK) @ Bt(bf16, NxK)^T
// EPI: 0 = none, 1 = exact gelu.  128x128 tile, BK=64, 4 waves of 64x64.
// ---------------------------------------------------------------------------
template <int K, int N, int EPI>
__global__ __launch_bounds__(256) void gemm128(const unsigned short* __restrict__ A,
                                               const unsigned short* __restrict__ Bt,
                                               unsigned short* __restrict__ C) {
    __shared__ unsigned short As[128 * 64];
    __shared__ unsigned short Bs[128 * 64];
    const int t = threadIdx.x;
    const int r0 = blockIdx.x * 128, c0 = blockIdx.y * 128;
    const int wv = t >> 6, lane = t & 63, q = lane >> 4, l16 = lane & 15;
    const int wr = (wv >> 1) * 64, wc = (wv & 1) * 64;
    f32x4 acc[4][4] = {};

    for (int k0 = 0; k0 < K; k0 += 64) {
        __syncthreads();
        stage<128>(A,  (size_t)r0, K, k0, As, wv, lane);
        stage<128>(Bt, (size_t)c0, K, k0, Bs, wv, lane);
        __builtin_amdgcn_s_waitcnt(0);
        __syncthreads();
        #pragma unroll
        for (int kk2 = 0; kk2 < 2; ++kk2) {
            s16x8 af[4], bfr[4];
            #pragma unroll
            for (int mf = 0; mf < 4; ++mf)
                af[mf] = fragld(As, wr + mf * 16 + l16, kk2 * 4 + q);
            #pragma unroll
            for (int nf = 0; nf < 4; ++nf)
                bfr[nf] = fragld(Bs, wc + nf * 16 + l16, kk2 * 4 + q);
            #pragma unroll
            for (int mf = 0; mf < 4; ++mf)
                #pragma unroll
                for (int nf = 0; nf < 4; ++nf)
                    acc[mf][nf] = __builtin_amdgcn_mfma_f32_16x16x32_bf16(af[mf], bfr[nf], acc[mf][nf], 0, 0, 0);
        }
    }

    #pragma unroll
    for (int mf = 0; mf < 4; ++mf)
        #pragma unroll
        for (int nf = 0; nf < 4; ++nf) {
            const int cg = c0 + wc + nf * 16 + l16;
            #pragma unroll
            for (int r = 0; r < 4; ++r) {
                const int rg = r0 + wr + mf * 16 + q * 4 + r;
                float v = acc[mf][nf][r];
                if (EPI == 1) v = 0.5f * v * (1.f + erff(v * 0.70710678118654752f));
                C[(size_t)rg * N + cg] = f2bf(v);
            }
        }
}

// ---------------------------------------------------------------------------
// gemm_ln<K,WBF>: out = LN(A(bf16,MxK) @ Bt(bf16,256xK)^T + res) ; N=256.
// BM=32, BN=256, 4 waves each 32 rows x 64 cols; fused row LN across waves.
// ---------------------------------------------------------------------------
template <int K, bool WBF>
__global__ __launch_bounds__(256) void gemm_ln(const unsigned short* __restrict__ A,
                                               const unsigned short* __restrict__ Bt,
                                               const float* __restrict__ res,
                                               const float* __restrict__ gamma,
                                               const float* __restrict__ beta,
                                               float* __restrict__ outf,
                                               unsigned short* __restrict__ outb) {
    __shared__ unsigned short As[32 * 64];
    __shared__ unsigned short Bs[256 * 64];
    __shared__ float2 partial[4][32];
    __shared__ float2 stats[32];
    const int t = threadIdx.x, r0 = blockIdx.x * 32;
    const int wv = t >> 6, lane = t & 63, q = lane >> 4, l16 = lane & 15;
    const int wc = wv * 64;
    f32x4 acc[2][4] = {};

    for (int k0 = 0; k0 < K; k0 += 64) {
        __syncthreads();
        stage<32>(A, (size_t)r0, K, k0, As, wv, lane);
        stage<256>(Bt, 0, K, k0, Bs, wv, lane);
        __builtin_amdgcn_s_waitcnt(0);
        __syncthreads();
        #pragma unroll
        for (int kk2 = 0; kk2 < 2; ++kk2) {
            s16x8 af[2], bfr[4];
            #pragma unroll
            for (int mf = 0; mf < 2; ++mf)
                af[mf] = fragld(As, mf * 16 + l16, kk2 * 4 + q);
            #pragma unroll
            for (int nf = 0; nf < 4; ++nf)
                bfr[nf] = fragld(Bs, wc + nf * 16 + l16, kk2 * 4 + q);
            #pragma unroll
            for (int mf = 0; mf < 2; ++mf)
                #pragma unroll
                for (int nf = 0; nf < 4; ++nf)
                    acc[mf][nf] = __builtin_amdgcn_mfma_f32_16x16x32_bf16(af[mf], bfr[nf], acc[mf][nf], 0, 0, 0);
        }
    }

    // + residual (before LN stats)
    #pragma unroll
    for (int mf = 0; mf < 2; ++mf)
        #pragma unroll
        for (int nf = 0; nf < 4; ++nf) {
            const int cg = wc + nf * 16 + l16;
            #pragma unroll
            for (int r = 0; r < 4; ++r) {
                const int rg = r0 + mf * 16 + q * 4 + r;
                acc[mf][nf][r] += res[(size_t)rg * NH + cg];
            }
        }

    // per-row partial sums over this wave's 64 cols (reduce across 16-lane quad)
    #pragma unroll
    for (int mf = 0; mf < 2; ++mf) {
        float s[4] = {0.f, 0.f, 0.f, 0.f}, ss[4] = {0.f, 0.f, 0.f, 0.f};
        #pragma unroll
        for (int nf = 0; nf < 4; ++nf)
            #pragma unroll
            for (int r = 0; r < 4; ++r) {
                float v = acc[mf][nf][r];
                s[r] += v; ss[r] += v * v;
            }
        #pragma unroll
        for (int off = 1; off < 16; off <<= 1)
            #pragma unroll
            for (int r = 0; r < 4; ++r) {
                s[r]  += __shfl_xor(s[r],  off);
                ss[r] += __shfl_xor(ss[r], off);
            }
        if (l16 == 0)
            #pragma unroll
            for (int r = 0; r < 4; ++r)
                partial[wv][mf * 16 + q * 4 + r] = make_float2(s[r], ss[r]);
    }
    __syncthreads();
    if (t < 32) {
        float s = 0.f, ss = 0.f;
        #pragma unroll
        for (int w = 0; w < 4; ++w) { s += partial[w][t].x; ss += partial[w][t].y; }
        float mu  = s * (1.f / 256.f);
        float var = ss * (1.f / 256.f) - mu * mu;
        stats[t] = make_float2(mu, rsqrtf(var + LN_EPS));
    }
    __syncthreads();

    #pragma unroll
    for (int mf = 0; mf < 2; ++mf)
        #pragma unroll
        for (int nf = 0; nf < 4; ++nf) {
            const int cg = wc + nf * 16 + l16;
            const float g = gamma[cg], b = beta[cg];
            #pragma unroll
            for (int r = 0; r < 4; ++r) {
                const int rl = mf * 16 + q * 4 + r;
                const float2 st = stats[rl];
                float v = (acc[mf][nf][r] - st.x) * st.y * g + b;
                outf[(size_t)(r0 + rl) * NH + cg] = v;
                if (WBF) outb[(size_t)(r0 + rl) * NH + cg] = f2bf(v);
            }
        }
}

// ---------------------------------------------------------------------------
// FUSED qkv-GEMM + block-dense attention. One block per group (32 nodes).
// Phase 1 (GEMM, no LDS staging, no barriers): each wave computes the group's
//   32 rows x 192 cols of qkv = Xbf[32x256] @ WqkvT^T. A held in registers
//   (16 dwordx4/lane), B streamed from L2 in coalesced register fragments.
//   C-frags written bf16 into LDS qkv tile (stride LDR=772).
// Phase 2 (attention): round-6 register-blocked attention reading the LDS
//   tile in place. Thread (h=t>>5, u=t&31): score rows {(u&7)+8di} x cols
//   {(u>>3)+4dj}; softmax in registers via shfl_xor(8/16); P via padded
//   bf16 LDS tile (stride 34); PV d-cols (u>>3)*8+0..7.
// All LDS patterns hand-checked <=2-way (772*2B = 386 dw === 2 mod 32).
// ---------------------------------------------------------------------------
#define LDR 772
__global__ __launch_bounds__(256) void qkvattn(const unsigned short* __restrict__ Xb,
                                               const unsigned short* __restrict__ WqkvT,
                                               unsigned short* __restrict__ att) {
    __shared__ unsigned short s[32 * LDR];          // 48.25 KB: group qkv
    __shared__ unsigned short pt[8 * 32 * 34];      // 17.0 KB: P per head
    const int g = blockIdx.x;
    const int t = threadIdx.x;
    const int wv = t >> 6, lane = t & 63, q = lane >> 4, l16 = lane & 15;

    // ---- phase 1: qkv GEMM ----
    // A preload: rows l16, l16+16 of the group, all 8 k-chunks for this q.
    const unsigned short* ab = Xb + ((size_t)g * 32 + l16) * D + q * 8;
    s16x8 areg[2][8];
    #pragma unroll
    for (int mf = 0; mf < 2; ++mf)
        #pragma unroll
        for (int kk = 0; kk < 8; ++kk)
            areg[mf][kk] = *(const s16x8*)&ab[mf * 16 * D + kk * 32];

    #pragma unroll 2
    for (int ct = 0; ct < 12; ++ct) {
        const int cg = wv * 192 + ct * 16 + l16;
        const unsigned short* bp = WqkvT + (size_t)cg * D + q * 8;
        s16x8 breg[8];
        #pragma unroll
        for (int kk = 0; kk < 8; ++kk)
            breg[kk] = *(const s16x8*)&bp[kk * 32];
        f32x4 acc[2] = {};
        #pragma unroll
        for (int kk = 0; kk < 8; ++kk) {
            acc[0] = __builtin_amdgcn_mfma_f32_16x16x32_bf16(areg[0][kk], breg[kk], acc[0], 0, 0, 0);
            acc[1] = __builtin_amdgcn_mfma_f32_16x16x32_bf16(areg[1][kk], breg[kk], acc[1], 0, 0, 0);
        }
        #pragma unroll
        for (int mf = 0; mf < 2; ++mf)
            #pragma unroll
            for (int r = 0; r < 4; ++r)
                s[(mf * 16 + q * 4 + r) * LDR + cg] = f2bf(acc[mf][r]);
    }
    __syncthreads();

    // ---- phase 2: attention ----
    const int h = t >> 5, u = t & 31;
    const int ub = u & 7;          // row set: ub + 8*di
    const int us = u >> 3;         // score cols: us + 4*dj ; PV d0 = us*8
    const int qc = h * 96;         // q col base; k at +32; v at +64

    float sc[4][8];
    #pragma unroll
    for (int di = 0; di < 4; ++di)
        #pragma unroll
        for (int dj = 0; dj < 8; ++dj) sc[di][dj] = 0.f;

    for (int kq = 0; kq < 8; ++kq) {
        float qv[4][4];
        #pragma unroll
        for (int di = 0; di < 4; ++di) {
            uint2 v = *(const uint2*)&s[(ub + 8 * di) * LDR + qc + 4 * kq];
            qv[di][0] = bflo(v.x); qv[di][1] = bfhi(v.x);
            qv[di][2] = bflo(v.y); qv[di][3] = bfhi(v.y);
        }
        #pragma unroll
        for (int dj = 0; dj < 8; ++dj) {
            uint2 v = *(const uint2*)&s[(us + 4 * dj) * LDR + qc + 32 + 4 * kq];
            float kv[4];
            kv[0] = bflo(v.x); kv[1] = bfhi(v.x);
            kv[2] = bflo(v.y); kv[3] = bfhi(v.y);
            #pragma unroll
            for (int di = 0; di < 4; ++di)
                #pragma unroll
                for (int kk = 0; kk < 4; ++kk)
                    sc[di][dj] = fmaf(qv[di][kk], kv[kk], sc[di][dj]);
        }
    }

    #pragma unroll
    for (int di = 0; di < 4; ++di) {
        float m = sc[di][0];
        #pragma unroll
        for (int dj = 1; dj < 8; ++dj) m = fmaxf(m, sc[di][dj]);
        m = fmaxf(m, __shfl_xor(m, 8));
        m = fmaxf(m, __shfl_xor(m, 16));
        float sum = 0.f;
        #pragma unroll
        for (int dj = 0; dj < 8; ++dj) {
            float e = __expf((sc[di][dj] - m) * 0.17677669529663687f);
            sc[di][dj] = e;
            sum += e;
        }
        sum += __shfl_xor(sum, 8);
        sum += __shfl_xor(sum, 16);
        float inv = 1.f / sum;
        const int rb = h * 1088 + (ub + 8 * di) * 34;
        #pragma unroll
        for (int dj = 0; dj < 8; ++dj)
            pt[rb + us + 4 * dj] = f2bf(sc[di][dj] * inv);
    }
    __syncthreads();

    const int vc = qc + 64, d0 = us * 8;
    float o[4][8];
    #pragma unroll
    for (int di = 0; di < 4; ++di)
        #pragma unroll
        for (int dd = 0; dd < 8; ++dd) o[di][dd] = 0.f;

    for (int j = 0; j < 32; ++j) {
        float pv[4];
        #pragma unroll
        for (int di = 0; di < 4; ++di)
            pv[di] = bf2f(pt[h * 1088 + (ub + 8 * di) * 34 + j]);
        #pragma unroll
        for (int dq = 0; dq < 2; ++dq) {
            uint2 v = *(const uint2*)&s[j * LDR + vc + d0 + 4 * dq];
            float v0 = bflo(v.x), v1 = bfhi(v.x), v2 = bflo(v.y), v3 = bfhi(v.y);
            #pragma unroll
            for (int di = 0; di < 4; ++di) {
                o[di][dq * 4 + 0] = fmaf(pv[di], v0, o[di][dq * 4 + 0]);
                o[di][dq * 4 + 1] = fmaf(pv[di], v1, o[di][dq * 4 + 1]);
                o[di][dq * 4 + 2] = fmaf(pv[di], v2, o[di][dq * 4 + 2]);
                o[di][dq * 4 + 3] = fmaf(pv[di], v3, o[di][dq * 4 + 3]);
            }
        }
    }

    #pragma unroll
    for (int di = 0; di < 4; ++di) {
        const int i = ub + 8 * di;
        s16x8 ov;
        #pragma unroll
        for (int dd = 0; dd < 8; ++dd) ov[dd] = (short)f2bf(o[di][dd]);
        *(s16x8*)&att[(size_t)(g * 32 + i) * NH + h * 32 + d0] = ov;
    }
}

// ---------------------------------------------------------------------------
extern "C" void kernel_launch(void* const* d_in, const int* in_sizes, int n_in,
                              void* d_out, int out_size, void* d_ws, size_t ws_size,
                              hipStream_t stream) {
    const float* X      = (const float*)d_in[0];
    const float* W_qkv  = (const float*)d_in[2];
    const float* W_o    = (const float*)d_in[3];
    const float* ln1_g  = (const float*)d_in[4];
    const float* ln1_b  = (const float*)d_in[5];
    const float* W_i    = (const float*)d_in[6];
    const float* W_out2 = (const float*)d_in[7];
    const float* ln2_g  = (const float*)d_in[8];
    const float* ln2_b  = (const float*)d_in[9];
    float* out = (float*)d_out;

    char* ws = (char*)d_ws;
    unsigned short* Xbf   = (unsigned short*)(ws);                 //  8.0 MB
    unsigned short* attb  = (unsigned short*)(ws + 33554432);      //  8.0 MB
    float*          pref  = (float*)         (ws + 41943040);      // 16.0 MB
    unsigned short* preb  = (unsigned short*)(ws + 58720256);      //  8.0 MB
    unsigned short* WqkvT = (unsigned short*)(ws + 67108864);
    unsigned short* WoT   = (unsigned short*)(ws + 67502080);
    unsigned short* WiT   = (unsigned short*)(ws + 67633152);
    unsigned short* Wo2T  = (unsigned short*)(ws + 68157440);
    unsigned short* interb = (unsigned short*)(ws);                // 33.5 MB alias (Xbf dead)

    dim3 blk(256);
    hipLaunchKernelGGL(prep, dim3(768 + V * D / 4 / 256), blk, 0, stream,
                       X, Xbf, W_qkv, W_o, W_i, W_out2, WqkvT, WoT, WiT, Wo2T);

    hipLaunchKernelGGL(qkvattn, dim3(V / 32), blk, 0, stream, Xbf, WqkvT, attb);
    hipLaunchKernelGGL((gemm_ln<D, true>), dim3(V / 32), blk, 0, stream,
                       attb, WoT, X, ln1_g, ln1_b, pref, preb);
    hipLaunchKernelGGL((gemm128<D, IDIM, 1>), dim3(V / 128, IDIM / 128), blk, 0, stream,
                       preb, WiT, interb);
    hipLaunchKernelGGL((gemm_ln<IDIM, false>), dim3(V / 32), blk, 0, stream,
                       interb, Wo2T, pref, ln2_g, ln2_b, out, (unsigned short*)nullptr);
}

// Round 8
// 169.531 us; speedup vs baseline: 1.0891x; 1.0891x over previous
//
#include <hip/hip_runtime.h>
#include <math.h>

#define V 16384
#define D 256
#define NH 256
#define THREE_NH 768
#define IDIM 1024
#define LN_EPS 1e-12f

typedef short s16x8 __attribute__((ext_vector_type(8)));
typedef float f32x4 __attribute__((ext_vector_type(4)));

__device__ inline unsigned short f2bf(float f) {
    unsigned u = __float_as_uint(f);
    u += 0x7fffu + ((u >> 16) & 1u);          // RNE
    return (unsigned short)(u >> 16);
}
__device__ inline float bf2f(unsigned short s) {
    return __uint_as_float(((unsigned)s) << 16);
}
__device__ inline float bflo(unsigned v) { return __uint_as_float(v << 16); }
__device__ inline float bfhi(unsigned v) { return __uint_as_float(v & 0xffff0000u); }

// async global->LDS, 16B per lane. LDS dest = wave-uniform base + lane*16.
__device__ inline void gl2lds16(const unsigned short* g, unsigned short* l) {
    __builtin_amdgcn_global_load_lds(
        (__attribute__((address_space(1))) void*)(g),
        (__attribute__((address_space(3))) void*)(l), 16, 0, 0);
}

// Stage ROWS_T x 64 bf16 tile (row-major, leading dim ldk) into LDS.
// 16B chunk c of row r stored at chunk slot c ^ (r&7) (XOR swizzle on the
// global side; LDS write order stays lane-contiguous for global_load_lds).
template <int ROWS_T>
__device__ inline void stage(const unsigned short* __restrict__ src, size_t row0,
                             int ldk, int k0, unsigned short* lds, int wv, int lane) {
    constexpr int PER_WAVE = ROWS_T / 32;     // 1KB segments per wave
    #pragma unroll
    for (int i = 0; i < PER_WAVE; ++i) {
        const int seg = wv * PER_WAVE + i;
        const int r = seg * 8 + (lane >> 3);
        const int c = (lane & 7) ^ (r & 7);
        gl2lds16(src + (row0 + (size_t)r) * ldk + k0 + c * 8, lds + seg * 512);
    }
}

// read one 8-elem bf16 fragment (16B) for (row, chunk) from swizzled tile
__device__ inline s16x8 fragld(const unsigned short* lds, int row, int chunk) {
    return *(const s16x8*)&lds[row * 64 + ((chunk ^ (row & 7)) << 3)];
}

// ---------------------------------------------------------------------------
// prep: one launch for all conversions.
// blocks [0,768): W transposes (fp32 KxN -> bf16 NxK); [768,4864): X -> bf16.
// ---------------------------------------------------------------------------
__global__ __launch_bounds__(256) void prep(const float* __restrict__ X,
                                            unsigned short* __restrict__ Xb,
                                            const float* __restrict__ Wqkv,
                                            const float* __restrict__ Wo,
                                            const float* __restrict__ Wi,
                                            const float* __restrict__ Wo2,
                                            unsigned short* __restrict__ WqkvT,
                                            unsigned short* __restrict__ WoT,
                                            unsigned short* __restrict__ WiT,
                                            unsigned short* __restrict__ Wo2T) {
    const int b = blockIdx.x, t = threadIdx.x;
    if (b >= 768) {
        int i = (b - 768) * 256 + t;
        float4 v = ((const float4*)X)[i];
        ushort4 o;
        o.x = f2bf(v.x); o.y = f2bf(v.y); o.z = f2bf(v.z); o.w = f2bf(v.w);
        ((ushort4*)Xb)[i] = o;
        return;
    }
    __shared__ float tile[32][33];
    const float* W; unsigned short* Wt; int K, N, bx, by;
    if (b < 192)      { W = Wqkv; Wt = WqkvT; K = 256;  N = 768;  bx = b & 7;          by = b >> 3; }
    else if (b < 256) { W = Wo;   Wt = WoT;   K = 256;  N = 256;  bx = (b - 192) & 7;  by = (b - 192) >> 3; }
    else if (b < 512) { W = Wi;   Wt = WiT;   K = 256;  N = 1024; bx = (b - 256) & 7;  by = (b - 256) >> 3; }
    else              { W = Wo2;  Wt = Wo2T;  K = 1024; N = 256;  bx = (b - 512) & 31; by = (b - 512) >> 5; }
    const int k0 = bx * 32, n0 = by * 32;
    #pragma unroll
    for (int p = 0; p < 4; ++p) {
        int idx = t + p * 256, r = idx >> 5, c = idx & 31;
        tile[r][c] = W[(size_t)(k0 + r) * N + n0 + c];
    }
    __syncthreads();
    #pragma unroll
    for (int p = 0; p < 4; ++p) {
        int idx = t + p * 256, r = idx >> 5, c = idx & 31;
        Wt[(size_t)(n0 + r) * K + k0 + c] = f2bf(tile[c][r]);
    }
}

// ---------------------------------------------------------------------------
// gemm128<K,N,EPI>: C(bf16, MxN) = A(bf16, MxK) @ Bt(bf16, NxK)^T
// EPI: 0 = none, 1 = exact gelu.  128x128 tile, BK=64, 4 waves of 64x64.
// ---------------------------------------------------------------------------
template <int K, int N, int EPI>
__global__ __launch_bounds__(256) void gemm128(const unsigned short* __restrict__ A,
                                               const unsigned short* __restrict__ Bt,
                                               unsigned short* __restrict__ C) {
    __shared__ unsigned short As[128 * 64];
    __shared__ unsigned short Bs[128 * 64];
    const int t = threadIdx.x;
    const int r0 = blockIdx.x * 128, c0 = blockIdx.y * 128;
    const int wv = t >> 6, lane = t & 63, q = lane >> 4, l16 = lane & 15;
    const int wr = (wv >> 1) * 64, wc = (wv & 1) * 64;
    f32x4 acc[4][4] = {};

    for (int k0 = 0; k0 < K; k0 += 64) {
        __syncthreads();
        stage<128>(A,  (size_t)r0, K, k0, As, wv, lane);
        stage<128>(Bt, (size_t)c0, K, k0, Bs, wv, lane);
        __builtin_amdgcn_s_waitcnt(0);
        __syncthreads();
        #pragma unroll
        for (int kk2 = 0; kk2 < 2; ++kk2) {
            s16x8 af[4], bfr[4];
            #pragma unroll
            for (int mf = 0; mf < 4; ++mf)
                af[mf] = fragld(As, wr + mf * 16 + l16, kk2 * 4 + q);
            #pragma unroll
            for (int nf = 0; nf < 4; ++nf)
                bfr[nf] = fragld(Bs, wc + nf * 16 + l16, kk2 * 4 + q);
            #pragma unroll
            for (int mf = 0; mf < 4; ++mf)
                #pragma unroll
                for (int nf = 0; nf < 4; ++nf)
                    acc[mf][nf] = __builtin_amdgcn_mfma_f32_16x16x32_bf16(af[mf], bfr[nf], acc[mf][nf], 0, 0, 0);
        }
    }

    #pragma unroll
    for (int mf = 0; mf < 4; ++mf)
        #pragma unroll
        for (int nf = 0; nf < 4; ++nf) {
            const int cg = c0 + wc + nf * 16 + l16;
            #pragma unroll
            for (int r = 0; r < 4; ++r) {
                const int rg = r0 + wr + mf * 16 + q * 4 + r;
                float v = acc[mf][nf][r];
                if (EPI == 1) v = 0.5f * v * (1.f + erff(v * 0.70710678118654752f));
                C[(size_t)rg * N + cg] = f2bf(v);
            }
        }
}

// ---------------------------------------------------------------------------
// gemm_ln<K,OUTF,RESBF>: out = LN(A(bf16,MxK) @ Bt(bf16,256xK)^T + res); N=256.
// BM=32, BN=256, 4 waves each 32 rows x 64 cols; fused row LN across waves.
// OUTF: write fp32 out, else bf16. RESBF: residual is bf16, else fp32.
// ---------------------------------------------------------------------------
template <int K, bool OUTF, bool RESBF>
__global__ __launch_bounds__(256) void gemm_ln(const unsigned short* __restrict__ A,
                                               const unsigned short* __restrict__ Bt,
                                               const void* __restrict__ resv,
                                               const float* __restrict__ gamma,
                                               const float* __restrict__ beta,
                                               float* __restrict__ outf,
                                               unsigned short* __restrict__ outb) {
    __shared__ unsigned short As[32 * 64];
    __shared__ unsigned short Bs[256 * 64];
    __shared__ float2 partial[4][32];
    __shared__ float2 stats[32];
    const int t = threadIdx.x, r0 = blockIdx.x * 32;
    const int wv = t >> 6, lane = t & 63, q = lane >> 4, l16 = lane & 15;
    const int wc = wv * 64;
    f32x4 acc[2][4] = {};

    for (int k0 = 0; k0 < K; k0 += 64) {
        __syncthreads();
        stage<32>(A, (size_t)r0, K, k0, As, wv, lane);
        stage<256>(Bt, 0, K, k0, Bs, wv, lane);
        __builtin_amdgcn_s_waitcnt(0);
        __syncthreads();
        #pragma unroll
        for (int kk2 = 0; kk2 < 2; ++kk2) {
            s16x8 af[2], bfr[4];
            #pragma unroll
            for (int mf = 0; mf < 2; ++mf)
                af[mf] = fragld(As, mf * 16 + l16, kk2 * 4 + q);
            #pragma unroll
            for (int nf = 0; nf < 4; ++nf)
                bfr[nf] = fragld(Bs, wc + nf * 16 + l16, kk2 * 4 + q);
            #pragma unroll
            for (int mf = 0; mf < 2; ++mf)
                #pragma unroll
                for (int nf = 0; nf < 4; ++nf)
                    acc[mf][nf] = __builtin_amdgcn_mfma_f32_16x16x32_bf16(af[mf], bfr[nf], acc[mf][nf], 0, 0, 0);
        }
    }

    // + residual (before LN stats)
    #pragma unroll
    for (int mf = 0; mf < 2; ++mf)
        #pragma unroll
        for (int nf = 0; nf < 4; ++nf) {
            const int cg = wc + nf * 16 + l16;
            #pragma unroll
            for (int r = 0; r < 4; ++r) {
                const size_t idx = (size_t)(r0 + mf * 16 + q * 4 + r) * NH + cg;
                float rv;
                if (RESBF) rv = bf2f(((const unsigned short*)resv)[idx]);
                else       rv = ((const float*)resv)[idx];
                acc[mf][nf][r] += rv;
            }
        }

    // per-row partial sums over this wave's 64 cols (reduce across 16-lane quad)
    #pragma unroll
    for (int mf = 0; mf < 2; ++mf) {
        float s[4] = {0.f, 0.f, 0.f, 0.f}, ss[4] = {0.f, 0.f, 0.f, 0.f};
        #pragma unroll
        for (int nf = 0; nf < 4; ++nf)
            #pragma unroll
            for (int r = 0; r < 4; ++r) {
                float v = acc[mf][nf][r];
                s[r] += v; ss[r] += v * v;
            }
        #pragma unroll
        for (int off = 1; off < 16; off <<= 1)
            #pragma unroll
            for (int r = 0; r < 4; ++r) {
                s[r]  += __shfl_xor(s[r],  off);
                ss[r] += __shfl_xor(ss[r], off);
            }
        if (l16 == 0)
            #pragma unroll
            for (int r = 0; r < 4; ++r)
                partial[wv][mf * 16 + q * 4 + r] = make_float2(s[r], ss[r]);
    }
    __syncthreads();
    if (t < 32) {
        float s = 0.f, ss = 0.f;
        #pragma unroll
        for (int w = 0; w < 4; ++w) { s += partial[w][t].x; ss += partial[w][t].y; }
        float mu  = s * (1.f / 256.f);
        float var = ss * (1.f / 256.f) - mu * mu;
        stats[t] = make_float2(mu, rsqrtf(var + LN_EPS));
    }
    __syncthreads();

    #pragma unroll
    for (int mf = 0; mf < 2; ++mf)
        #pragma unroll
        for (int nf = 0; nf < 4; ++nf) {
            const int cg = wc + nf * 16 + l16;
            const float g = gamma[cg], b = beta[cg];
            #pragma unroll
            for (int r = 0; r < 4; ++r) {
                const int rl = mf * 16 + q * 4 + r;
                const float2 st = stats[rl];
                float v = (acc[mf][nf][r] - st.x) * st.y * g + b;
                const size_t idx = (size_t)(r0 + rl) * NH + cg;
                if (OUTF) outf[idx] = v;
                else      outb[idx] = f2bf(v);
            }
        }
}

// ---------------------------------------------------------------------------
// block-dense attention: one block per GROUP (all 8 heads), 256 threads.
// Register-blocked: thread (h = t>>5, u = t&31) computes score rows
// {(u&7)+8*di} x cols {(u>>3)+4*dj}; softmax fully in registers via
// __shfl_xor(8/16); P -> padded bf16 LDS tile; PV with d-cols (u>>3)*8+0..7.
// LDS row stride 776: all access phases <=2-way banks.
// ---------------------------------------------------------------------------
#define LDR 776
__global__ __launch_bounds__(256) void attn(const unsigned short* __restrict__ qkv,
                                            unsigned short* __restrict__ att) {
    __shared__ unsigned short s[32 * LDR];          // 48.5 KB: group qkv
    __shared__ unsigned short pt[8 * 32 * 34];      // 17.0 KB: P per head, stride 34
    const int g = blockIdx.x;
    const int t = threadIdx.x;
    const int h = t >> 5, u = t & 31;
    const int ub = u & 7;          // row set: ub + 8*di
    const int us = u >> 3;         // score cols: us + 4*dj ; PV d0 = us*8
    const int qc = h * 96;         // q col base; k at +32; v at +64

    // ---- load: group's qkv is 24576 contiguous ushorts; 16B per lane ----
    const unsigned short* src = qkv + (size_t)g * 32 * THREE_NH;
    #pragma unroll
    for (int pp = 0; pp < 12; ++pp) {
        int c = t + pp * 256;                  // chunk id 0..3071
        int row = c / 96, col8 = c % 96;
        s16x8 vv = *(const s16x8*)&src[c * 8];
        *(s16x8*)&s[row * LDR + col8 * 8] = vv;
    }
    __syncthreads();

    // ---- scores: acc[di][dj], k read 4-at-a-time (b64) ----
    float acc[4][8];
    #pragma unroll
    for (int di = 0; di < 4; ++di)
        #pragma unroll
        for (int dj = 0; dj < 8; ++dj) acc[di][dj] = 0.f;

    for (int kq = 0; kq < 8; ++kq) {
        float qv[4][4];
        #pragma unroll
        for (int di = 0; di < 4; ++di) {
            uint2 v = *(const uint2*)&s[(ub + 8 * di) * LDR + qc + 4 * kq];
            qv[di][0] = bflo(v.x); qv[di][1] = bfhi(v.x);
            qv[di][2] = bflo(v.y); qv[di][3] = bfhi(v.y);
        }
        #pragma unroll
        for (int dj = 0; dj < 8; ++dj) {
            uint2 v = *(const uint2*)&s[(us + 4 * dj) * LDR + qc + 32 + 4 * kq];
            float kv[4];
            kv[0] = bflo(v.x); kv[1] = bfhi(v.x);
            kv[2] = bflo(v.y); kv[3] = bfhi(v.y);
            #pragma unroll
            for (int di = 0; di < 4; ++di)
                #pragma unroll
                for (int kk = 0; kk < 4; ++kk)
                    acc[di][dj] = fmaf(qv[di][kk], kv[kk], acc[di][dj]);
        }
    }

    // ---- softmax per row (scale folded into exp arg) ----
    #pragma unroll
    for (int di = 0; di < 4; ++di) {
        float m = acc[di][0];
        #pragma unroll
        for (int dj = 1; dj < 8; ++dj) m = fmaxf(m, acc[di][dj]);
        m = fmaxf(m, __shfl_xor(m, 8));
        m = fmaxf(m, __shfl_xor(m, 16));
        float sum = 0.f;
        #pragma unroll
        for (int dj = 0; dj < 8; ++dj) {
            float e = __expf((acc[di][dj] - m) * 0.17677669529663687f);
            acc[di][dj] = e;
            sum += e;
        }
        sum += __shfl_xor(sum, 8);
        sum += __shfl_xor(sum, 16);
        float inv = 1.f / sum;
        const int rb = h * 1088 + (ub + 8 * di) * 34;
        #pragma unroll
        for (int dj = 0; dj < 8; ++dj)
            pt[rb + us + 4 * dj] = f2bf(acc[di][dj] * inv);
    }
    __syncthreads();

    // ---- PV: o[di][8 d-cols], d0 = us*8 ----
    const int vc = qc + 64, d0 = us * 8;
    float o[4][8];
    #pragma unroll
    for (int di = 0; di < 4; ++di)
        #pragma unroll
        for (int dd = 0; dd < 8; ++dd) o[di][dd] = 0.f;

    for (int j = 0; j < 32; ++j) {
        float pv[4];
        #pragma unroll
        for (int di = 0; di < 4; ++di)
            pv[di] = bf2f(pt[h * 1088 + (ub + 8 * di) * 34 + j]);
        #pragma unroll
        for (int dq = 0; dq < 2; ++dq) {
            uint2 v = *(const uint2*)&s[j * LDR + vc + d0 + 4 * dq];
            float v0 = bflo(v.x), v1 = bfhi(v.x), v2 = bflo(v.y), v3 = bfhi(v.y);
            #pragma unroll
            for (int di = 0; di < 4; ++di) {
                o[di][dq * 4 + 0] = fmaf(pv[di], v0, o[di][dq * 4 + 0]);
                o[di][dq * 4 + 1] = fmaf(pv[di], v1, o[di][dq * 4 + 1]);
                o[di][dq * 4 + 2] = fmaf(pv[di], v2, o[di][dq * 4 + 2]);
                o[di][dq * 4 + 3] = fmaf(pv[di], v3, o[di][dq * 4 + 3]);
            }
        }
    }

    #pragma unroll
    for (int di = 0; di < 4; ++di) {
        const int i = ub + 8 * di;
        s16x8 ov;
        #pragma unroll
        for (int dd = 0; dd < 8; ++dd) ov[dd] = (short)f2bf(o[di][dd]);
        *(s16x8*)&att[(size_t)(g * 32 + i) * NH + h * 32 + d0] = ov;
    }
}

// ---------------------------------------------------------------------------
extern "C" void kernel_launch(void* const* d_in, const int* in_sizes, int n_in,
                              void* d_out, int out_size, void* d_ws, size_t ws_size,
                              hipStream_t stream) {
    const float* X      = (const float*)d_in[0];
    const float* W_qkv  = (const float*)d_in[2];
    const float* W_o    = (const float*)d_in[3];
    const float* ln1_g  = (const float*)d_in[4];
    const float* ln1_b  = (const float*)d_in[5];
    const float* W_i    = (const float*)d_in[6];
    const float* W_out2 = (const float*)d_in[7];
    const float* ln2_g  = (const float*)d_in[8];
    const float* ln2_b  = (const float*)d_in[9];
    float* out = (float*)d_out;

    char* ws = (char*)d_ws;
    unsigned short* Xbf   = (unsigned short*)(ws);                 //  8.0 MB
    unsigned short* qkvb  = (unsigned short*)(ws + 8388608);       // 25.2 MB
    unsigned short* attb  = (unsigned short*)(ws + 33554432);      //  8.0 MB
    unsigned short* preb  = (unsigned short*)(ws + 58720256);      //  8.0 MB
    unsigned short* WqkvT = (unsigned short*)(ws + 67108864);
    unsigned short* WoT   = (unsigned short*)(ws + 67502080);
    unsigned short* WiT   = (unsigned short*)(ws + 67633152);
    unsigned short* Wo2T  = (unsigned short*)(ws + 68157440);
    unsigned short* interb = (unsigned short*)(ws);                // 33.5 MB alias (Xbf+qkvb dead)

    dim3 blk(256);
    hipLaunchKernelGGL(prep, dim3(768 + V * D / 4 / 256), blk, 0, stream,
                       X, Xbf, W_qkv, W_o, W_i, W_out2, WqkvT, WoT, WiT, Wo2T);

    hipLaunchKernelGGL((gemm128<D, THREE_NH, 0>), dim3(V / 128, THREE_NH / 128), blk, 0, stream,
                       Xbf, WqkvT, qkvb);
    hipLaunchKernelGGL(attn, dim3(V / 32), blk, 0, stream, qkvb, attb);
    hipLaunchKernelGGL((gemm_ln<D, false, false>), dim3(V / 32), blk, 0, stream,
                       attb, WoT, (const void*)X, ln1_g, ln1_b, (float*)nullptr, preb);
    hipLaunchKernelGGL((gemm128<D, IDIM, 1>), dim3(V / 128, IDIM / 128), blk, 0, stream,
                       preb, WiT, interb);
    hipLaunchKernelGGL((gemm_ln<IDIM, true, true>), dim3(V / 32), blk, 0, stream,
                       interb, Wo2T, (const void*)preb, ln2_g, ln2_b, out, (unsigned short*)nullptr);
}

// Round 9
// 164.274 us; speedup vs baseline: 1.1240x; 1.0320x over previous
//
#include <hip/hip_runtime.h>
#include <math.h>

#define V 16384
#define D 256
#define NH 256
#define THREE_NH 768
#define IDIM 1024
#define LN_EPS 1e-12f

typedef short s16x8 __attribute__((ext_vector_type(8)));
typedef float f32x4 __attribute__((ext_vector_type(4)));

__device__ inline unsigned short f2bf(float f) {
    unsigned u = __float_as_uint(f);
    u += 0x7fffu + ((u >> 16) & 1u);          // RNE
    return (unsigned short)(u >> 16);
}
__device__ inline float bf2f(unsigned short s) {
    return __uint_as_float(((unsigned)s) << 16);
}
__device__ inline float bflo(unsigned v) { return __uint_as_float(v << 16); }
__device__ inline float bfhi(unsigned v) { return __uint_as_float(v & 0xffff0000u); }

// async global->LDS, 16B per lane. LDS dest = wave-uniform base + lane*16.
__device__ inline void gl2lds16(const unsigned short* g, unsigned short* l) {
    __builtin_amdgcn_global_load_lds(
        (__attribute__((address_space(1))) void*)(g),
        (__attribute__((address_space(3))) void*)(l), 16, 0, 0);
}

// Stage ROWS_T x 64 bf16 tile (row-major, leading dim ldk) into LDS.
// 16B chunk c of row r stored at chunk slot c ^ (r&7) (XOR swizzle on the
// global side; LDS write order stays lane-contiguous for global_load_lds).
template <int ROWS_T>
__device__ inline void stage(const unsigned short* __restrict__ src, size_t row0,
                             int ldk, int k0, unsigned short* lds, int wv, int lane) {
    constexpr int PER_WAVE = ROWS_T / 32;     // 1KB segments per wave
    #pragma unroll
    for (int i = 0; i < PER_WAVE; ++i) {
        const int seg = wv * PER_WAVE + i;
        const int r = seg * 8 + (lane >> 3);
        const int c = (lane & 7) ^ (r & 7);
        gl2lds16(src + (row0 + (size_t)r) * ldk + k0 + c * 8, lds + seg * 512);
    }
}

// read one 8-elem bf16 fragment (16B) for (row, chunk) from swizzled tile
__device__ inline s16x8 fragld(const unsigned short* lds, int row, int chunk) {
    return *(const s16x8*)&lds[row * 64 + ((chunk ^ (row & 7)) << 3)];
}

// ---------------------------------------------------------------------------
// prep: one launch for all conversions.
// blocks [0,768): W transposes (fp32 KxN -> bf16 NxK); [768,4864): X -> bf16.
// ---------------------------------------------------------------------------
__global__ __launch_bounds__(256) void prep(const float* __restrict__ X,
                                            unsigned short* __restrict__ Xb,
                                            const float* __restrict__ Wqkv,
                                            const float* __restrict__ Wo,
                                            const float* __restrict__ Wi,
                                            const float* __restrict__ Wo2,
                                            unsigned short* __restrict__ WqkvT,
                                            unsigned short* __restrict__ WoT,
                                            unsigned short* __restrict__ WiT,
                                            unsigned short* __restrict__ Wo2T) {
    const int b = blockIdx.x, t = threadIdx.x;
    if (b >= 768) {
        int i = (b - 768) * 256 + t;
        float4 v = ((const float4*)X)[i];
        ushort4 o;
        o.x = f2bf(v.x); o.y = f2bf(v.y); o.z = f2bf(v.z); o.w = f2bf(v.w);
        ((ushort4*)Xb)[i] = o;
        return;
    }
    __shared__ float tile[32][33];
    const float* W; unsigned short* Wt; int K, N, bx, by;
    if (b < 192)      { W = Wqkv; Wt = WqkvT; K = 256;  N = 768;  bx = b & 7;          by = b >> 3; }
    else if (b < 256) { W = Wo;   Wt = WoT;   K = 256;  N = 256;  bx = (b - 192) & 7;  by = (b - 192) >> 3; }
    else if (b < 512) { W = Wi;   Wt = WiT;   K = 256;  N = 1024; bx = (b - 256) & 7;  by = (b - 256) >> 3; }
    else              { W = Wo2;  Wt = Wo2T;  K = 1024; N = 256;  bx = (b - 512) & 31; by = (b - 512) >> 5; }
    const int k0 = bx * 32, n0 = by * 32;
    #pragma unroll
    for (int p = 0; p < 4; ++p) {
        int idx = t + p * 256, r = idx >> 5, c = idx & 31;
        tile[r][c] = W[(size_t)(k0 + r) * N + n0 + c];
    }
    __syncthreads();
    #pragma unroll
    for (int p = 0; p < 4; ++p) {
        int idx = t + p * 256, r = idx >> 5, c = idx & 31;
        Wt[(size_t)(n0 + r) * K + k0 + c] = f2bf(tile[c][r]);
    }
}

// ---------------------------------------------------------------------------
// gemm128<K,N,EPI>: C(bf16, MxN) = A(bf16, MxK) @ Bt(bf16, NxK)^T
// EPI: 0 = none, 1 = exact gelu.  128x128 tile, BK=64, 4 waves of 64x64.
// ---------------------------------------------------------------------------
template <int K, int N, int EPI>
__global__ __launch_bounds__(256) void gemm128(const unsigned short* __restrict__ A,
                                               const unsigned short* __restrict__ Bt,
                                               unsigned short* __restrict__ C) {
    __shared__ unsigned short As[128 * 64];
    __shared__ unsigned short Bs[128 * 64];
    const int t = threadIdx.x;
    const int r0 = blockIdx.x * 128, c0 = blockIdx.y * 128;
    const int wv = t >> 6, lane = t & 63, q = lane >> 4, l16 = lane & 15;
    const int wr = (wv >> 1) * 64, wc = (wv & 1) * 64;
    f32x4 acc[4][4] = {};

    for (int k0 = 0; k0 < K; k0 += 64) {
        __syncthreads();
        stage<128>(A,  (size_t)r0, K, k0, As, wv, lane);
        stage<128>(Bt, (size_t)c0, K, k0, Bs, wv, lane);
        __builtin_amdgcn_s_waitcnt(0);
        __syncthreads();
        #pragma unroll
        for (int kk2 = 0; kk2 < 2; ++kk2) {
            s16x8 af[4], bfr[4];
            #pragma unroll
            for (int mf = 0; mf < 4; ++mf)
                af[mf] = fragld(As, wr + mf * 16 + l16, kk2 * 4 + q);
            #pragma unroll
            for (int nf = 0; nf < 4; ++nf)
                bfr[nf] = fragld(Bs, wc + nf * 16 + l16, kk2 * 4 + q);
            #pragma unroll
            for (int mf = 0; mf < 4; ++mf)
                #pragma unroll
                for (int nf = 0; nf < 4; ++nf)
                    acc[mf][nf] = __builtin_amdgcn_mfma_f32_16x16x32_bf16(af[mf], bfr[nf], acc[mf][nf], 0, 0, 0);
        }
    }

    #pragma unroll
    for (int mf = 0; mf < 4; ++mf)
        #pragma unroll
        for (int nf = 0; nf < 4; ++nf) {
            const int cg = c0 + wc + nf * 16 + l16;
            #pragma unroll
            for (int r = 0; r < 4; ++r) {
                const int rg = r0 + wr + mf * 16 + q * 4 + r;
                float v = acc[mf][nf][r];
                if (EPI == 1) v = 0.5f * v * (1.f + erff(v * 0.70710678118654752f));
                C[(size_t)rg * N + cg] = f2bf(v);
            }
        }
}

// ---------------------------------------------------------------------------
// gemm_ln<K,OUTF,RESBF>: out = LN(A(bf16,MxK) @ Bt(bf16,256xK)^T + res); N=256.
// BM=32, BN=256, 4 waves each 32 rows x 64 cols; fused row LN across waves.
// ---------------------------------------------------------------------------
template <int K, bool OUTF, bool RESBF>
__global__ __launch_bounds__(256) void gemm_ln(const unsigned short* __restrict__ A,
                                               const unsigned short* __restrict__ Bt,
                                               const void* __restrict__ resv,
                                               const float* __restrict__ gamma,
                                               const float* __restrict__ beta,
                                               float* __restrict__ outf,
                                               unsigned short* __restrict__ outb) {
    __shared__ unsigned short As[32 * 64];
    __shared__ unsigned short Bs[256 * 64];
    __shared__ float2 partial[4][32];
    __shared__ float2 stats[32];
    const int t = threadIdx.x, r0 = blockIdx.x * 32;
    const int wv = t >> 6, lane = t & 63, q = lane >> 4, l16 = lane & 15;
    const int wc = wv * 64;
    f32x4 acc[2][4] = {};

    for (int k0 = 0; k0 < K; k0 += 64) {
        __syncthreads();
        stage<32>(A, (size_t)r0, K, k0, As, wv, lane);
        stage<256>(Bt, 0, K, k0, Bs, wv, lane);
        __builtin_amdgcn_s_waitcnt(0);
        __syncthreads();
        #pragma unroll
        for (int kk2 = 0; kk2 < 2; ++kk2) {
            s16x8 af[2], bfr[4];
            #pragma unroll
            for (int mf = 0; mf < 2; ++mf)
                af[mf] = fragld(As, mf * 16 + l16, kk2 * 4 + q);
            #pragma unroll
            for (int nf = 0; nf < 4; ++nf)
                bfr[nf] = fragld(Bs, wc + nf * 16 + l16, kk2 * 4 + q);
            #pragma unroll
            for (int mf = 0; mf < 2; ++mf)
                #pragma unroll
                for (int nf = 0; nf < 4; ++nf)
                    acc[mf][nf] = __builtin_amdgcn_mfma_f32_16x16x32_bf16(af[mf], bfr[nf], acc[mf][nf], 0, 0, 0);
        }
    }

    // + residual (before LN stats)
    #pragma unroll
    for (int mf = 0; mf < 2; ++mf)
        #pragma unroll
        for (int nf = 0; nf < 4; ++nf) {
            const int cg = wc + nf * 16 + l16;
            #pragma unroll
            for (int r = 0; r < 4; ++r) {
                const size_t idx = (size_t)(r0 + mf * 16 + q * 4 + r) * NH + cg;
                float rv;
                if (RESBF) rv = bf2f(((const unsigned short*)resv)[idx]);
                else       rv = ((const float*)resv)[idx];
                acc[mf][nf][r] += rv;
            }
        }

    // per-row partial sums over this wave's 64 cols (reduce across 16-lane quad)
    #pragma unroll
    for (int mf = 0; mf < 2; ++mf) {
        float s[4] = {0.f, 0.f, 0.f, 0.f}, ss[4] = {0.f, 0.f, 0.f, 0.f};
        #pragma unroll
        for (int nf = 0; nf < 4; ++nf)
            #pragma unroll
            for (int r = 0; r < 4; ++r) {
                float v = acc[mf][nf][r];
                s[r] += v; ss[r] += v * v;
            }
        #pragma unroll
        for (int off = 1; off < 16; off <<= 1)
            #pragma unroll
            for (int r = 0; r < 4; ++r) {
                s[r]  += __shfl_xor(s[r],  off);
                ss[r] += __shfl_xor(ss[r], off);
            }
        if (l16 == 0)
            #pragma unroll
            for (int r = 0; r < 4; ++r)
                partial[wv][mf * 16 + q * 4 + r] = make_float2(s[r], ss[r]);
    }
    __syncthreads();
    if (t < 32) {
        float s = 0.f, ss = 0.f;
        #pragma unroll
        for (int w = 0; w < 4; ++w) { s += partial[w][t].x; ss += partial[w][t].y; }
        float mu  = s * (1.f / 256.f);
        float var = ss * (1.f / 256.f) - mu * mu;
        stats[t] = make_float2(mu, rsqrtf(var + LN_EPS));
    }
    __syncthreads();

    #pragma unroll
    for (int mf = 0; mf < 2; ++mf)
        #pragma unroll
        for (int nf = 0; nf < 4; ++nf) {
            const int cg = wc + nf * 16 + l16;
            const float g = gamma[cg], b = beta[cg];
            #pragma unroll
            for (int r = 0; r < 4; ++r) {
                const int rl = mf * 16 + q * 4 + r;
                const float2 st = stats[rl];
                float v = (acc[mf][nf][r] - st.x) * st.y * g + b;
                const size_t idx = (size_t)(r0 + rl) * NH + cg;
                if (OUTF) outf[idx] = v;
                else      outb[idx] = f2bf(v);
            }
        }
}

// ---------------------------------------------------------------------------
// FUSED attention + W_o GEMM + LN1. One block per group (32 nodes).
// Phase A (attention, = round-6 kernel): qkv group tile in LDS (stride 776),
//   register-blocked scores, register softmax via shfl_xor(8/16), P via
//   padded bf16 LDS, PV -> o[4][8] in registers.
// Bridge: o written bf16 into an LDS A-tile in stage()/fragld() layout
//   (4 tiles of 32x64, XOR chunk swizzle), overlaying the dead qkv region.
// Phase B (= gemm_ln<256> body): A from LDS, B=WoT staged per k0, residual X
//   (fp32), fused LN, write bf16 preb.
// LDS: max(qkv 48.5K + P 17K, at 16K + Bs 32K + stats 1.3K) = 65.5 KB.
// ---------------------------------------------------------------------------
#define LDR 776
__global__ __launch_bounds__(256) void attln(const unsigned short* __restrict__ qkv,
                                             const unsigned short* __restrict__ WoT,
                                             const float* __restrict__ X,
                                             const float* __restrict__ gamma,
                                             const float* __restrict__ beta,
                                             unsigned short* __restrict__ preb) {
    __shared__ unsigned short smem[33536 + 320];    // 24832 (s) + 8704 (pt) + stats
    unsigned short* s  = smem;                      // attn qkv tile, stride LDR
    unsigned short* pt = smem + 24832;              // P tiles, 8*32*34
    unsigned short* at = smem;                      // phase B: A tile (4 x 32x64)
    unsigned short* Bs = smem + 8192;               // phase B: B stage (256x64)
    float2* partial = (float2*)(smem + 24832);      // overlays pt (dead in phase B)
    float2* stats   = (float2*)(smem + 24832 + 512);

    const int g = blockIdx.x;
    const int t = threadIdx.x;
    const int h = t >> 5, u = t & 31;
    const int ub = u & 7;          // row set: ub + 8*di
    const int us = u >> 3;         // score cols: us + 4*dj ; PV d0 = us*8
    const int qc = h * 96;         // q col base; k at +32; v at +64

    // ---- load: group's qkv is 24576 contiguous ushorts; 16B per lane ----
    const unsigned short* src = qkv + (size_t)g * 32 * THREE_NH;
    #pragma unroll
    for (int pp = 0; pp < 12; ++pp) {
        int c = t + pp * 256;                  // chunk id 0..3071
        int row = c / 96, col8 = c % 96;
        s16x8 vv = *(const s16x8*)&src[c * 8];
        *(s16x8*)&s[row * LDR + col8 * 8] = vv;
    }
    __syncthreads();

    // ---- scores ----
    float sc[4][8];
    #pragma unroll
    for (int di = 0; di < 4; ++di)
        #pragma unroll
        for (int dj = 0; dj < 8; ++dj) sc[di][dj] = 0.f;

    for (int kq = 0; kq < 8; ++kq) {
        float qv[4][4];
        #pragma unroll
        for (int di = 0; di < 4; ++di) {
            uint2 v = *(const uint2*)&s[(ub + 8 * di) * LDR + qc + 4 * kq];
            qv[di][0] = bflo(v.x); qv[di][1] = bfhi(v.x);
            qv[di][2] = bflo(v.y); qv[di][3] = bfhi(v.y);
        }
        #pragma unroll
        for (int dj = 0; dj < 8; ++dj) {
            uint2 v = *(const uint2*)&s[(us + 4 * dj) * LDR + qc + 32 + 4 * kq];
            float kv[4];
            kv[0] = bflo(v.x); kv[1] = bfhi(v.x);
            kv[2] = bflo(v.y); kv[3] = bfhi(v.y);
            #pragma unroll
            for (int di = 0; di < 4; ++di)
                #pragma unroll
                for (int kk = 0; kk < 4; ++kk)
                    sc[di][dj] = fmaf(qv[di][kk], kv[kk], sc[di][dj]);
        }
    }

    // ---- softmax per row ----
    #pragma unroll
    for (int di = 0; di < 4; ++di) {
        float m = sc[di][0];
        #pragma unroll
        for (int dj = 1; dj < 8; ++dj) m = fmaxf(m, sc[di][dj]);
        m = fmaxf(m, __shfl_xor(m, 8));
        m = fmaxf(m, __shfl_xor(m, 16));
        float sum = 0.f;
        #pragma unroll
        for (int dj = 0; dj < 8; ++dj) {
            float e = __expf((sc[di][dj] - m) * 0.17677669529663687f);
            sc[di][dj] = e;
            sum += e;
        }
        sum += __shfl_xor(sum, 8);
        sum += __shfl_xor(sum, 16);
        float inv = 1.f / sum;
        const int rb = h * 1088 + (ub + 8 * di) * 34;
        #pragma unroll
        for (int dj = 0; dj < 8; ++dj)
            pt[rb + us + 4 * dj] = f2bf(sc[di][dj] * inv);
    }
    __syncthreads();

    // ---- PV ----
    const int vc = qc + 64, d0 = us * 8;
    float o[4][8];
    #pragma unroll
    for (int di = 0; di < 4; ++di)
        #pragma unroll
        for (int dd = 0; dd < 8; ++dd) o[di][dd] = 0.f;

    for (int j = 0; j < 32; ++j) {
        float pv[4];
        #pragma unroll
        for (int di = 0; di < 4; ++di)
            pv[di] = bf2f(pt[h * 1088 + (ub + 8 * di) * 34 + j]);
        #pragma unroll
        for (int dq = 0; dq < 2; ++dq) {
            uint2 v = *(const uint2*)&s[j * LDR + vc + d0 + 4 * dq];
            float v0 = bflo(v.x), v1 = bfhi(v.x), v2 = bflo(v.y), v3 = bfhi(v.y);
            #pragma unroll
            for (int di = 0; di < 4; ++di) {
                o[di][dq * 4 + 0] = fmaf(pv[di], v0, o[di][dq * 4 + 0]);
                o[di][dq * 4 + 1] = fmaf(pv[di], v1, o[di][dq * 4 + 1]);
                o[di][dq * 4 + 2] = fmaf(pv[di], v2, o[di][dq * 4 + 2]);
                o[di][dq * 4 + 3] = fmaf(pv[di], v3, o[di][dq * 4 + 3]);
            }
        }
    }
    __syncthreads();   // all reads of s/pt done before overwriting with at

    // ---- bridge: o -> at (swizzled A layout) ----
    {
        const int col = h * 32 + d0;           // 8-col chunk this thread owns
        const int kb = col >> 6, c = (col & 63) >> 3;
        #pragma unroll
        for (int di = 0; di < 4; ++di) {
            const int i = ub + 8 * di;
            s16x8 ov;
            #pragma unroll
            for (int dd = 0; dd < 8; ++dd) ov[dd] = (short)f2bf(o[di][dd]);
            *(s16x8*)&at[kb * 2048 + i * 64 + ((c ^ (i & 7)) << 3)] = ov;
        }
    }

    // ---- phase B: pre = LN(at @ WoT^T + X), write bf16 ----
    const int wv = t >> 6, lane = t & 63, q = lane >> 4, l16 = lane & 15;
    const int wc = wv * 64;
    const int r0 = g * 32;
    f32x4 acc[2][4] = {};

    for (int k0 = 0; k0 < 256; k0 += 64) {
        __syncthreads();
        stage<256>(WoT, 0, 256, k0, Bs, wv, lane);
        __builtin_amdgcn_s_waitcnt(0);
        __syncthreads();
        const unsigned short* atk = at + (k0 >> 6) * 2048;
        #pragma unroll
        for (int kk2 = 0; kk2 < 2; ++kk2) {
            s16x8 af[2], bfr[4];
            #pragma unroll
            for (int mf = 0; mf < 2; ++mf)
                af[mf] = fragld(atk, mf * 16 + l16, kk2 * 4 + q);
            #pragma unroll
            for (int nf = 0; nf < 4; ++nf)
                bfr[nf] = fragld(Bs, wc + nf * 16 + l16, kk2 * 4 + q);
            #pragma unroll
            for (int mf = 0; mf < 2; ++mf)
                #pragma unroll
                for (int nf = 0; nf < 4; ++nf)
                    acc[mf][nf] = __builtin_amdgcn_mfma_f32_16x16x32_bf16(af[mf], bfr[nf], acc[mf][nf], 0, 0, 0);
        }
    }

    // + residual X (fp32)
    #pragma unroll
    for (int mf = 0; mf < 2; ++mf)
        #pragma unroll
        for (int nf = 0; nf < 4; ++nf) {
            const int cg = wc + nf * 16 + l16;
            #pragma unroll
            for (int r = 0; r < 4; ++r)
                acc[mf][nf][r] += X[(size_t)(r0 + mf * 16 + q * 4 + r) * NH + cg];
        }

    // LN partial sums
    #pragma unroll
    for (int mf = 0; mf < 2; ++mf) {
        float sp[4] = {0.f, 0.f, 0.f, 0.f}, ssp[4] = {0.f, 0.f, 0.f, 0.f};
        #pragma unroll
        for (int nf = 0; nf < 4; ++nf)
            #pragma unroll
            for (int r = 0; r < 4; ++r) {
                float v = acc[mf][nf][r];
                sp[r] += v; ssp[r] += v * v;
            }
        #pragma unroll
        for (int off = 1; off < 16; off <<= 1)
            #pragma unroll
            for (int r = 0; r < 4; ++r) {
                sp[r]  += __shfl_xor(sp[r],  off);
                ssp[r] += __shfl_xor(ssp[r], off);
            }
        if (l16 == 0)
            #pragma unroll
            for (int r = 0; r < 4; ++r)
                partial[wv * 32 + mf * 16 + q * 4 + r] = make_float2(sp[r], ssp[r]);
    }
    __syncthreads();
    if (t < 32) {
        float sv = 0.f, ssv = 0.f;
        #pragma unroll
        for (int w = 0; w < 4; ++w) { sv += partial[w * 32 + t].x; ssv += partial[w * 32 + t].y; }
        float mu  = sv * (1.f / 256.f);
        float var = ssv * (1.f / 256.f) - mu * mu;
        stats[t] = make_float2(mu, rsqrtf(var + LN_EPS));
    }
    __syncthreads();

    #pragma unroll
    for (int mf = 0; mf < 2; ++mf)
        #pragma unroll
        for (int nf = 0; nf < 4; ++nf) {
            const int cg = wc + nf * 16 + l16;
            const float gm = gamma[cg], bt = beta[cg];
            #pragma unroll
            for (int r = 0; r < 4; ++r) {
                const int rl = mf * 16 + q * 4 + r;
                const float2 st = stats[rl];
                float v = (acc[mf][nf][r] - st.x) * st.y * gm + bt;
                preb[(size_t)(r0 + rl) * NH + cg] = f2bf(v);
            }
        }
}

// ---------------------------------------------------------------------------
extern "C" void kernel_launch(void* const* d_in, const int* in_sizes, int n_in,
                              void* d_out, int out_size, void* d_ws, size_t ws_size,
                              hipStream_t stream) {
    const float* X      = (const float*)d_in[0];
    const float* W_qkv  = (const float*)d_in[2];
    const float* W_o    = (const float*)d_in[3];
    const float* ln1_g  = (const float*)d_in[4];
    const float* ln1_b  = (const float*)d_in[5];
    const float* W_i    = (const float*)d_in[6];
    const float* W_out2 = (const float*)d_in[7];
    const float* ln2_g  = (const float*)d_in[8];
    const float* ln2_b  = (const float*)d_in[9];
    float* out = (float*)d_out;

    char* ws = (char*)d_ws;
    unsigned short* Xbf   = (unsigned short*)(ws);                 //  8.0 MB
    unsigned short* qkvb  = (unsigned short*)(ws + 8388608);       // 25.2 MB
    unsigned short* preb  = (unsigned short*)(ws + 58720256);      //  8.0 MB
    unsigned short* WqkvT = (unsigned short*)(ws + 67108864);
    unsigned short* WoT   = (unsigned short*)(ws + 67502080);
    unsigned short* WiT   = (unsigned short*)(ws + 67633152);
    unsigned short* Wo2T  = (unsigned short*)(ws + 68157440);
    unsigned short* interb = (unsigned short*)(ws);                // 33.5 MB alias (Xbf+qkvb dead)

    dim3 blk(256);
    hipLaunchKernelGGL(prep, dim3(768 + V * D / 4 / 256), blk, 0, stream,
                       X, Xbf, W_qkv, W_o, W_i, W_out2, WqkvT, WoT, WiT, Wo2T);

    hipLaunchKernelGGL((gemm128<D, THREE_NH, 0>), dim3(V / 128, THREE_NH / 128), blk, 0, stream,
                       Xbf, WqkvT, qkvb);
    hipLaunchKernelGGL(attln, dim3(V / 32), blk, 0, stream,
                       qkvb, WoT, X, ln1_g, ln1_b, preb);
    hipLaunchKernelGGL((gemm128<D, IDIM, 1>), dim3(V / 128, IDIM / 128), blk, 0, stream,
                       preb, WiT, interb);
    hipLaunchKernelGGL((gemm_ln<IDIM, true, true>), dim3(V / 32), blk, 0, stream,
                       interb, Wo2T, (const void*)preb, ln2_g, ln2_b, out, (unsigned short*)nullptr);
}